// Round 17
// baseline (136.980 us; speedup 1.0000x reference)
//
#include <hip/hip_runtime.h>
#include <hip/hip_bf16.h>
#include <stdint.h>

// Problem constants
#define SEQL   2048
#define NBATCH 2
#define BSZ    4096   // NBATCH*SEQL
#define DMODEL 1024
#define NH     16
#define DK     64
#define NBH    32     // NBATCH*NH
#define NCHUNK2 20    // sum over qi2 of ceil((4qi2+4)/8), qi2 in 0..7

typedef __attribute__((ext_vector_type(8)))  short short8;
typedef __attribute__((ext_vector_type(4)))  short shortx4;
typedef __attribute__((ext_vector_type(4)))  float f32x4;
typedef __attribute__((ext_vector_type(16))) float f32x16;
typedef __attribute__((ext_vector_type(4)))  unsigned uint4v;
union PU { uint4v u; short8 s; };

__device__ __forceinline__ short f2b(float f) {   // f32 -> bf16 (RNE)
  unsigned u = __float_as_uint(f);
  u = (u + 0x7FFF + ((u >> 16) & 1)) >> 16;
  return (short)u;
}
__device__ __forceinline__ float b2f(short s) {
  return __uint_as_float(((unsigned)(unsigned short)s) << 16);
}
__device__ __forceinline__ unsigned cvtpk(float lo, float hi) {
  unsigned r;
  asm("v_cvt_pk_bf16_f32 %0, %1, %2" : "=v"(r) : "v"(lo), "v"(hi));
  return r;
}
// swap a's upper-32-lane half with b's lower-32-lane half (in place)
#define PLSWAP(a_, b_) asm("v_permlane32_swap_b32 %0, %1" : "+v"(a_), "+v"(b_))

// async global->LDS, 16B per lane. LDS dest = wave-uniform base + lane*16.
__device__ __forceinline__ void g2l16(const void* g, void* l) {
  __builtin_amdgcn_global_load_lds(
      (__attribute__((address_space(1))) void*)(uintptr_t)g,
      (__attribute__((address_space(3))) void*)l, 16, 0, 0);
}

__device__ __forceinline__ f32x4 mfma16(short8 a, short8 b, f32x4 c) {
  return __builtin_amdgcn_mfma_f32_16x16x32_bf16(a, b, c, 0, 0, 0);
}
__device__ __forceinline__ f32x16 mfma32(short8 a, short8 b, f32x16 c) {
  return __builtin_amdgcn_mfma_f32_32x32x16_bf16(a, b, c, 0, 0, 0);
}

// ---------------------------------------------------------------- cvt f32->bf16
__global__ void cvt_all(const float* __restrict__ x,  const float* __restrict__ wq,
                        const float* __restrict__ wk, const float* __restrict__ wv,
                        const float* __restrict__ wo, short* __restrict__ xb,
                        short* __restrict__ wqkv, short* __restrict__ wob) {
  long idx = ((long)blockIdx.x * 256 + threadIdx.x) * 4;
  const float* s; short* d; long off;
  if (idx < 4194304L)      { s = x;  d = xb;             off = idx; }
  else if (idx < 5242880L) { s = wq; d = wqkv;           off = idx - 4194304L; }
  else if (idx < 6291456L) { s = wk; d = wqkv + 1048576; off = idx - 5242880L; }
  else if (idx < 7340032L) { s = wv; d = wqkv + 2097152; off = idx - 6291456L; }
  else                     { s = wo; d = wob;            off = idx - 7340032L; }
  float4 v = *(const float4*)(s + off);
  shortx4 r;
  r[0] = f2b(v.x); r[1] = f2b(v.y); r[2] = f2b(v.z); r[3] = f2b(v.w);
  *(shortx4*)(d + off) = r;
}

// ---------------------------------------------------------------- QKV GEMM, 256x192
// (R15 2-hazard schedule, measured best.)
__global__ __launch_bounds__(512, 1)
void gemm256(const short* __restrict__ A, const short* __restrict__ B,
             const int* __restrict__ tok, short* __restrict__ qh,
             short* __restrict__ kh, short* __restrict__ vlin) {
  __shared__ short As[2][16384];
  __shared__ short Bs[2][12288];
  int id = blockIdx.x;                    // 256 blocks
  int swz = (id & 7) * 32 + (id >> 3);    // XCD-bijective
  int bm = swz >> 4, bn = swz & 15;
  int brow = bm << 8, bcoln = bn * 192;
  int tid = threadIdx.x, w = tid >> 6;
  int wm = w >> 2, wn = w & 3;
  int lr = tid & 15, lg = (tid >> 4) & 3;
  const short* Abase = A + (long)brow * 1024;
  const short* Bbase = B + (long)bcoln * 1024;

  f32x4 acc[8][3];
#pragma unroll
  for (int mi = 0; mi < 8; ++mi)
#pragma unroll
    for (int ni = 0; ni < 3; ++ni) acc[mi][ni] = (f32x4){0.f, 0.f, 0.f, 0.f};

#define STGA(s_, kt_, buf_) do {                                                \
    int r_ = tid >> 3, gch_ = (tid & 7) ^ (r_ & 7);                             \
    g2l16(Abase + (long)((s_) * 64 + r_) * 1024 + (kt_) * 64 + gch_ * 8,        \
          &As[buf_][(s_) * 4096 + tid * 8]); } while (0)
#define STGB(s_, kt_, buf_) do {                                                \
    int r_ = tid >> 3, gch_ = (tid & 7) ^ (r_ & 7);                             \
    g2l16(Bbase + (long)((s_) * 64 + r_) * 1024 + (kt_) * 64 + gch_ * 8,        \
          &Bs[buf_][(s_) * 4096 + tid * 8]); } while (0)

  STGA(0,0,0); STGA(1,0,0); STGA(2,0,0); STGA(3,0,0);
  STGB(0,0,0); STGB(1,0,0); STGB(2,0,0);
  STGA(0,1,1); STGA(1,1,1); STGA(2,1,1); STGA(3,1,1);
  STGB(0,1,1); STGB(1,1,1); STGB(2,1,1);
  asm volatile("s_waitcnt vmcnt(7)" ::: "memory");
  __builtin_amdgcn_s_barrier();

  for (int kt = 0; kt < 16; ++kt) {
    int cur = kt & 1;
    const short* Ah = &As[cur][wm * 8192];
    const short* Bh = &Bs[cur][0];
    short8 a0[4][2], a1[4][2], bf[3][2];
#pragma unroll
    for (int mi = 0; mi < 4; ++mi) {
      int rin = mi * 16 + lr;
#pragma unroll
      for (int ks = 0; ks < 2; ++ks)
        a0[mi][ks] = *(const short8*)
            &Ah[rin * 64 + (((ks * 4 + lg) ^ (rin & 7)) << 3)];
    }
#pragma unroll
    for (int ni = 0; ni < 3; ++ni) {
      int ci = wn * 48 + ni * 16 + lr;
      int sub = ci >> 6, rin = ci & 63;
#pragma unroll
      for (int ks = 0; ks < 2; ++ks)
        bf[ni][ks] = *(const short8*)
            &Bh[sub * 4096 + rin * 64 + (((ks * 4 + lg) ^ (rin & 7)) << 3)];
    }
#pragma unroll
    for (int mi = 0; mi < 4; ++mi) {
      int rin = mi * 16 + lr;
#pragma unroll
      for (int ks = 0; ks < 2; ++ks)
        a1[mi][ks] = *(const short8*)
            &Ah[4096 + rin * 64 + (((ks * 4 + lg) ^ (rin & 7)) << 3)];
    }
    __builtin_amdgcn_s_setprio(1);
#pragma unroll
    for (int mi = 0; mi < 4; ++mi)
#pragma unroll
      for (int ni = 0; ni < 3; ++ni)
#pragma unroll
        for (int ks = 0; ks < 2; ++ks)
          acc[mi][ni] = mfma16(a0[mi][ks], bf[ni][ks], acc[mi][ni]);
    __builtin_amdgcn_s_setprio(0);
    asm volatile("s_waitcnt lgkmcnt(0)" ::: "memory");
    __builtin_amdgcn_s_barrier();
    if (kt + 2 < 16) {
      STGA(0, kt + 2, cur); STGA(1, kt + 2, cur);
      STGA(2, kt + 2, cur); STGA(3, kt + 2, cur);
      STGB(0, kt + 2, cur); STGB(1, kt + 2, cur); STGB(2, kt + 2, cur);
    }
    __builtin_amdgcn_s_setprio(1);
#pragma unroll
    for (int mi = 0; mi < 4; ++mi)
#pragma unroll
      for (int ni = 0; ni < 3; ++ni)
#pragma unroll
        for (int ks = 0; ks < 2; ++ks)
          acc[mi + 4][ni] = mfma16(a1[mi][ks], bf[ni][ks], acc[mi + 4][ni]);
    __builtin_amdgcn_s_setprio(0);
    if (kt + 1 < 16) {
      if (kt + 2 < 16) asm volatile("s_waitcnt vmcnt(7)" ::: "memory");
      else             asm volatile("s_waitcnt vmcnt(0)" ::: "memory");
    }
    __builtin_amdgcn_s_barrier();
  }
#undef STGA
#undef STGB

  // ---- epilogue: Q/K -> RoPE + head-split; V -> linear for vtrans.
  int sbase = brow + wm * 128;
#pragma unroll
  for (int ni = 0; ni < 3; ++ni) {
    int gcol = bcoln + wn * 48 + ni * 16 + lr;
    int mat = gcol >> 10;
    int cin = gcol & 1023;
    if (mat == 2) {
#pragma unroll
      for (int mi = 0; mi < 8; ++mi)
#pragma unroll
        for (int rr = 0; rr < 4; ++rr) {
          int grow = sbase + mi * 16 + lg * 4 + rr;
          vlin[(long)grow * 1024 + cin] = f2b(acc[mi][ni][rr]);
        }
    } else {
      short* dst = mat ? kh : qh;
      float scale = mat ? 1.0f : 0.125f * 1.44269504f;
      int d = cin & 63, h = cin >> 6;
      int i = d >> 1;
      int odd = d & 1;
      float frev = exp2f(-(float)i * 0.41524101186f) * 0.15915494309f;
#pragma unroll
      for (int mi = 0; mi < 8; ++mi)
#pragma unroll
        for (int rr = 0; rr < 4; ++rr) {
          int grow = sbase + mi * 16 + lg * 4 + rr;
          int s = grow & 2047, b = grow >> 11;
          float pos = (float)tok[s];
          float rev = pos * frev;
          float fr = rev - floorf(rev);
          float sn, cs;
          asm("v_sin_f32 %0, %1" : "=v"(sn) : "v"(fr));
          asm("v_cos_f32 %0, %1" : "=v"(cs) : "v"(fr));
          float v = acc[mi][ni][rr];
          float p = __shfl_xor(v, 1);
          float out = odd ? (p * sn + v * cs) : (v * cs - p * sn);
          dst[((long)(b * 16 + h) * 2048 + s) * 64 + d] = f2b(out * scale);
        }
    }
  }
}

// ---------------------------------------------------------------- final GEMM, 128x128, BK=64, 2-hazard
__global__ __launch_bounds__(256, 2)
void gemm_fin(const short* __restrict__ A, const short* __restrict__ B,
              float* __restrict__ C) {
  __shared__ short As[2][8192];
  __shared__ short Bs[2][8192];
  int bm = blockIdx.x >> 3, bn = blockIdx.x & 7;
  int tid = threadIdx.x, w = tid >> 6, l = tid & 63;
  int wm = w >> 1, wn = w & 1;
  int lr = l & 15, lg = l >> 4;
  int brow = bm << 7, bcol = bn << 7;
  const short* Abase = A + (long)brow * 1024;
  const short* Bbase = B + (long)bcol * 1024;

  const f32x4 fz = {0.f, 0.f, 0.f, 0.f};
  f32x4 acc[4][4];
#pragma unroll
  for (int xi = 0; xi < 4; ++xi)
#pragma unroll
    for (int yi = 0; yi < 4; ++yi) acc[xi][yi] = fz;

#define FSTG(kt_, buf_) do {                                                    \
    _Pragma("unroll")                                                           \
    for (int i_ = 0; i_ < 4; ++i_) {                                            \
      int idx_ = i_ * 256 + tid;                                                \
      int r_ = idx_ >> 3, gch_ = (idx_ & 7) ^ (r_ & 7);                         \
      g2l16(Abase + (long)r_ * 1024 + (kt_) * 64 + gch_ * 8,                    \
            &As[buf_][idx_ * 8]);                                               \
      g2l16(Bbase + (long)r_ * 1024 + (kt_) * 64 + gch_ * 8,                    \
            &Bs[buf_][idx_ * 8]);                                               \
    } } while (0)

  FSTG(0, 0);
  FSTG(1, 1);
  asm volatile("s_waitcnt vmcnt(8)" ::: "memory");
  __builtin_amdgcn_s_barrier();

  for (int kt = 0; kt < 16; ++kt) {
    int cur = kt & 1;
    short8 af[4][2], bfr[4][2];
#pragma unroll
    for (int xi = 0; xi < 4; ++xi) {
      int ar = wm * 64 + xi * 16 + lr;
      int br = wn * 64 + xi * 16 + lr;
#pragma unroll
      for (int ks = 0; ks < 2; ++ks) {
        af[xi][ks] = *(const short8*)
            &As[cur][ar * 64 + (((ks * 4 + lg) ^ (ar & 7)) << 3)];
        bfr[xi][ks] = *(const short8*)
            &Bs[cur][br * 64 + (((ks * 4 + lg) ^ (br & 7)) << 3)];
      }
    }
    __builtin_amdgcn_s_setprio(1);
#pragma unroll
    for (int xi = 0; xi < 4; ++xi)
#pragma unroll
      for (int yi = 0; yi < 4; ++yi)
        acc[xi][yi] = mfma16(af[xi][0], bfr[yi][0], acc[xi][yi]);
    __builtin_amdgcn_s_setprio(0);
    asm volatile("s_waitcnt lgkmcnt(0)" ::: "memory");
    __builtin_amdgcn_s_barrier();
    if (kt + 2 < 16) FSTG(kt + 2, cur);
    __builtin_amdgcn_s_setprio(1);
#pragma unroll
    for (int xi = 0; xi < 4; ++xi)
#pragma unroll
      for (int yi = 0; yi < 4; ++yi)
        acc[xi][yi] = mfma16(af[xi][1], bfr[yi][1], acc[xi][yi]);
    __builtin_amdgcn_s_setprio(0);
    if (kt + 1 < 16) {
      if (kt + 2 < 16) asm volatile("s_waitcnt vmcnt(8)" ::: "memory");
      else             asm volatile("s_waitcnt vmcnt(0)" ::: "memory");
    }
    __builtin_amdgcn_s_barrier();
  }
#undef FSTG

#pragma unroll
  for (int xi = 0; xi < 4; ++xi)
#pragma unroll
    for (int yi = 0; yi < 4; ++yi)
#pragma unroll
      for (int r = 0; r < 4; ++r) {
        int row = brow + wm * 64 + xi * 16 + lg * 4 + r;
        int col = bcol + wn * 64 + yi * 16 + lr;
        C[(long)row * 1024 + col] = acc[xi][yi][r];
      }
}

// ---------------------------------------------------------------- V transpose
__global__ void vtrans(const short* __restrict__ Vlin, short* __restrict__ Vt) {
  __shared__ short tile[64][72];
  int s0 = blockIdx.x * 64;
  int bh = blockIdx.y;
  int b = bh >> 4, h = bh & 15;
  int t = threadIdx.x;
  int r = t >> 2, c0 = (t & 3) * 16;
  const short* src = Vlin + ((long)(b * 2048 + s0 + r)) * 1024 + h * 64 + c0;
  *(short8*)&tile[r][c0]     = *(const short8*)src;
  *(short8*)&tile[r][c0 + 8] = *(const short8*)(src + 8);
  __syncthreads();
  int d = t >> 2, sc0 = (t & 3) * 16;
  short8 o0, o1;
#pragma unroll
  for (int j = 0; j < 8; ++j) { o0[j] = tile[sc0 + j][d]; o1[j] = tile[sc0 + 8 + j][d]; }
  short* dst = Vt + ((long)(bh * 64 + d)) * 2048 + s0 + sc0;
  *(short8*)dst       = o0;
  *(short8*)(dst + 8) = o1;
}

// ---------------------------------------------------------------- causal flash attention, split-KV, 2 q-groups/wave
// grid (NBH, 20): bh -> XCD pin; q-tiles of 256 rows (qi2 0..7), chunks
// heavy-first, nc=(qi2+2)>>1 (<=8 kv-tiles each). 4 waves; each wave owns
// 2 q-groups (rows q0b+32w and q0b+128+32w) sharing the SAME staged KV tile
// -> per-tile sync/stage overhead amortized over 2x q-rows, LDS unchanged
// (48KB, 3 blocks/CU). 3-deep pipeline, counted vmcnt(8). log2 domain.
__global__ __launch_bounds__(256, 3)
void attn_fwd(const short* __restrict__ Qh, const short* __restrict__ Kh,
              const short* __restrict__ Vt, short* __restrict__ poO,
              float* __restrict__ pmb, float* __restrict__ plb) {
  __shared__ short Ks[3][4096];
  __shared__ short Vs[3][4096];
  int bh = blockIdx.x;
  int xr = NCHUNK2 - 1 - blockIdx.y;        // heavy chunks first
  int qi, c = xr, nc = 1;
  for (qi = 0; qi < 8; ++qi) { nc = (qi + 2) >> 1; if (c < nc) break; c -= nc; }
  int n = 4 * qi + 4;                       // 64-kv tiles for this 256-q tile
  int t0 = (c * n) / nc, t1 = ((c + 1) * n) / nc;
  int q0b = qi << 8;
  int tid = threadIdx.x, w = tid >> 6, l = tid & 63;
  int ql = l & 31, hi = l >> 5;
  const short* Qb = Qh + (long)bh * (2048 * 64);
  const short* Kb = Kh + (long)bh * (2048 * 64);
  const short* Vb = Vt + (long)bh * (64 * 2048);
  int qw0 = q0b + 32 * w;                   // group 0 rows
  int qw1 = q0b + 128 + 32 * w;             // group 1 rows
  int qg0 = qw0 + ql, qg1 = qw1 + ql;
  int pid = bh * NCHUNK2 + xr;

  short8 qf0[4], qf1[4];
#pragma unroll
  for (int kc = 0; kc < 4; ++kc) {
    qf0[kc] = *(const short8*)(Qb + (long)qg0 * 64 + kc * 16 + hi * 8);
    qf1[kc] = *(const short8*)(Qb + (long)qg1 * 64 + kc * 16 + hi * 8);
  }

  f32x16 oA0, oB0, oA1, oB1;
#pragma unroll
  for (int r = 0; r < 16; ++r) { oA0[r] = 0.f; oB0[r] = 0.f; oA1[r] = 0.f; oB1[r] = 0.f; }
  float m0 = -1e30f, l0 = 0.f, m1 = -1e30f, l1 = 0.f;

#define STAGE(t_, bufi_) do {                                                   \
    int s0_ = (t_) << 6;                                                        \
    _Pragma("unroll")                                                           \
    for (int i_ = 0; i_ < 2; ++i_) {                                            \
      int c_ = w + 4 * i_;                                                      \
      int g_ = c_ >> 2, cc_ = c_ & 3;                                           \
      g2l16(Kb + ((long)(s0_ + g_ * 32 + ql)) * 64 + cc_ * 16 + hi * 8,         \
            &Ks[bufi_][c_ * 512]);                                              \
      g2l16(Vb + ((long)(g_ * 32 + ql)) * 2048 + s0_ + cc_ * 16 + hi * 8,       \
            &Vs[bufi_][c_ * 512]);                                              \
    }                                                                           \
  } while (0)

// one softmax+PV body for one q-group at kv tile s0 (uses Ks/Vs[cur])
#define GBODY(qw_, qg_, qf_, m_, lsum_, oA_, oB_) do {                          \
    if (s0 <= (qw_) + 31) {                                                     \
      bool upper = (s0 + 32 <= (qw_) + 31);                                     \
      f32x16 sT0, sT1;                                                          \
      _Pragma("unroll")                                                         \
      for (int r = 0; r < 16; ++r) { sT0[r] = 0.f; sT1[r] = 0.f; }              \
      __builtin_amdgcn_s_setprio(1);                                            \
      _Pragma("unroll")                                                         \
      for (int kc = 0; kc < 4; ++kc) {                                          \
        short8 k0 = *(const short8*)&Ks[cur][(kc * 64 + l) * 8];                \
        sT0 = mfma32(k0, qf_[kc], sT0);                                         \
      }                                                                         \
      if (upper) {                                                              \
        _Pragma("unroll")                                                       \
        for (int kc = 0; kc < 4; ++kc) {                                        \
          short8 k1 = *(const short8*)&Ks[cur][((4 + kc) * 64 + l) * 8];        \
          sT1 = mfma32(k1, qf_[kc], sT1);                                       \
        }                                                                       \
      }                                                                         \
      __builtin_amdgcn_s_setprio(0);                                            \
      if (s0 + 63 > (qw_)) {                                                    \
        _Pragma("unroll")                                                       \
        for (int r = 0; r < 16; ++r) {                                          \
          int kvl = (r & 3) + 8 * (r >> 2) + 4 * hi;                            \
          if (s0 + kvl > (qg_)) sT0[r] = -1e30f;                                \
        }                                                                       \
        if (upper) {                                                            \
          _Pragma("unroll")                                                     \
          for (int r = 0; r < 16; ++r) {                                        \
            int kvl = (r & 3) + 8 * (r >> 2) + 4 * hi;                          \
            if (s0 + 32 + kvl > (qg_)) sT1[r] = -1e30f;                         \
          }                                                                     \
        }                                                                       \
      }                                                                         \
      float pmax = sT0[0];                                                      \
      _Pragma("unroll")                                                         \
      for (int r = 1; r < 16; ++r) pmax = fmaxf(pmax, sT0[r]);                  \
      if (upper) {                                                              \
        _Pragma("unroll")                                                       \
        for (int r = 0; r < 16; ++r) pmax = fmaxf(pmax, sT1[r]);                \
      }                                                                         \
      pmax = fmaxf(pmax, __shfl_xor(pmax, 32));                                 \
      if (__any(pmax > (m_) + 11.5416f)) {                                      \
        float mn = fmaxf((m_), pmax);                                           \
        float sf = exp2f((m_) - mn);                                            \
        (m_) = mn;                                                              \
        (lsum_) *= sf;                                                          \
        _Pragma("unroll")                                                       \
        for (int r = 0; r < 16; ++r) {                                          \
          int row = (r & 3) + 8 * (r >> 2) + 4 * hi;                            \
          float fo = __shfl(sf, row);                                           \
          oA_[r] *= fo; oB_[r] *= fo;                                           \
        }                                                                       \
      }                                                                         \
      float rs = 0.f;                                                           \
      _Pragma("unroll")                                                         \
      for (int r = 0; r < 16; ++r) {                                            \
        float p = exp2f(sT0[r] - (m_));                                         \
        sT0[r] = p; rs += p;                                                    \
      }                                                                         \
      if (upper) {                                                              \
        _Pragma("unroll")                                                       \
        for (int r = 0; r < 16; ++r) {                                          \
          float p = exp2f(sT1[r] - (m_));                                       \
          sT1[r] = p; rs += p;                                                  \
        }                                                                       \
      }                                                                         \
      rs += __shfl_xor(rs, 32);                                                 \
      (lsum_) += rs;                                                            \
      short8 pa[4];                                                             \
      {                                                                         \
        unsigned cA[4], cB[4];                                                  \
        _Pragma("unroll")                                                       \
        for (int g = 0; g < 4; ++g) {                                           \
          cA[g] = cvtpk(sT0[4 * g], sT0[4 * g + 1]);                            \
          cB[g] = cvtpk(sT0[4 * g + 2], sT0[4 * g + 3]);                        \
        }                                                                       \
        PLSWAP(cA[0], cA[1]); PLSWAP(cB[0], cB[1]);                             \
        PLSWAP(cA[2], cA[3]); PLSWAP(cB[2], cB[3]);                             \
        PU p0; p0.u = (uint4v){cA[0], cB[0], cA[1], cB[1]}; pa[0] = p0.s;       \
        PU p1; p1.u = (uint4v){cA[2], cB[2], cA[3], cB[3]}; pa[1] = p1.s;       \
      }                                                                         \
      if (upper) {                                                              \
        unsigned cA[4], cB[4];                                                  \
        _Pragma("unroll")                                                       \
        for (int g = 0; g < 4; ++g) {                                           \
          cA[g] = cvtpk(sT1[4 * g], sT1[4 * g + 1]);                            \
          cB[g] = cvtpk(sT1[4 * g + 2], sT1[4 * g + 3]);                        \
        }                                                                       \
        PLSWAP(cA[0], cA[1]); PLSWAP(cB[0], cB[1]);                             \
        PLSWAP(cA[2], cA[3]); PLSWAP(cB[2], cB[3]);                             \
        PU p2; p2.u = (uint4v){cA[0], cB[0], cA[1], cB[1]}; pa[2] = p2.s;       \
        PU p3; p3.u = (uint4v){cA[2], cB[2], cA[3], cB[3]}; pa[3] = p3.s;       \
      }                                                                         \
      __builtin_amdgcn_s_setprio(1);                                            \
      _Pragma("unroll")                                                         \
      for (int kc = 0; kc < 2; ++kc) {                                          \
        short8 v0 = *(const short8*)&Vs[cur][(kc * 64 + l) * 8];                \
        short8 v1 = *(const short8*)&Vs[cur][((4 + kc) * 64 + l) * 8];          \
        oA_ = mfma32(pa[kc], v0, oA_);                                          \
        oB_ = mfma32(pa[kc], v1, oB_);                                          \
      }                                                                         \
      if (upper) {                                                              \
        _Pragma("unroll")                                                       \
        for (int kc = 2; kc < 4; ++kc) {                                        \
          short8 v0 = *(const short8*)&Vs[cur][(kc * 64 + l) * 8];              \
          short8 v1 = *(const short8*)&Vs[cur][((4 + kc) * 64 + l) * 8];        \
          oA_ = mfma32(pa[kc], v0, oA_);                                        \
          oB_ = mfma32(pa[kc], v1, oB_);                                        \
        }                                                                       \
      }                                                                         \
      __builtin_amdgcn_s_setprio(0);                                            \
    }                                                                           \
  } while (0)

  STAGE(t0, 0);
  if (t0 + 1 < t1) STAGE(t0 + 1, 1);
  int cur = 0;

  for (int t = t0; t < t1; ++t) {
    if (t + 2 < t1) {
      int nb = cur + 2; if (nb >= 3) nb -= 3;
      STAGE(t + 2, nb);
      asm volatile("s_waitcnt vmcnt(8)" ::: "memory");
    } else if (t + 1 < t1) {
      asm volatile("s_waitcnt vmcnt(4)" ::: "memory");
    } else {
      asm volatile("s_waitcnt vmcnt(0)" ::: "memory");
    }
    __builtin_amdgcn_s_barrier();
    int s0 = t << 6;
    GBODY(qw0, qg0, qf0, m0, l0, oA0, oB0);
    GBODY(qw1, qg1, qf1, m1, l1, oA1, oB1);
    asm volatile("s_waitcnt lgkmcnt(0)" ::: "memory");
    __builtin_amdgcn_s_barrier();
    ++cur; if (cur >= 3) cur -= 3;
  }
#undef STAGE
#undef GBODY

  if (hi == 0) {
    pmb[pid * 256 + w * 32 + ql]       = m0;
    plb[pid * 256 + w * 32 + ql]       = l0;
    pmb[pid * 256 + 128 + w * 32 + ql] = m1;
    plb[pid * 256 + 128 + w * 32 + ql] = l1;
  }
#pragma unroll
  for (int r = 0; r < 16; ++r) {
    int row = (r & 3) + 8 * (r >> 2) + 4 * hi;
    long base0 = ((long)pid * 256 + w * 32 + row) * 64;
    long base1 = ((long)pid * 256 + 128 + w * 32 + row) * 64;
    poO[base0 + ql]      = f2b(oA0[r]);
    poO[base0 + 32 + ql] = f2b(oB0[r]);
    poO[base1 + ql]      = f2b(oA1[r]);
    poO[base1 + 32 + ql] = f2b(oB1[r]);
  }
}

// ---------------------------------------------------------------- combine partials
// grid (64, NBH): qi2 = x>>3 (256-row tiles), sub = x&7 (32 rows each)
__global__ void attn_combine(const short* __restrict__ poO,
                             const float* __restrict__ pmb,
                             const float* __restrict__ plb,
                             short* __restrict__ Oh) {
  int x = blockIdx.x, bh = blockIdx.y;
  int qi = x >> 3, sub = x & 7;
  int t = threadIdx.x;
  int r = sub * 32 + (t >> 3);
  int d0 = (t & 7) * 8;
  int nc = (qi + 2) >> 1;
  int prefix = 0;
  for (int j = 0; j < qi; ++j) prefix += (j + 2) >> 1;
  int base = bh * NCHUNK2 + prefix;
  float M = -1e30f;
  for (int i = 0; i < nc; ++i)
    M = fmaxf(M, pmb[(base + i) * 256 + r]);
  float acc0 = 0, acc1 = 0, acc2 = 0, acc3 = 0, acc4 = 0, acc5 = 0, acc6 = 0, acc7 = 0;
  float den = 0.f;
  for (int i = 0; i < nc; ++i) {
    float wgt = exp2f(pmb[(base + i) * 256 + r] - M);
    den += wgt * plb[(base + i) * 256 + r];
    short8 ov = *(const short8*)&poO[((long)(base + i) * 256 + r) * 64 + d0];
    acc0 += wgt * b2f(ov[0]); acc1 += wgt * b2f(ov[1]);
    acc2 += wgt * b2f(ov[2]); acc3 += wgt * b2f(ov[3]);
    acc4 += wgt * b2f(ov[4]); acc5 += wgt * b2f(ov[5]);
    acc6 += wgt * b2f(ov[6]); acc7 += wgt * b2f(ov[7]);
  }
  float inv = 1.0f / den;
  int b = bh >> 4, h = bh & 15;
  int s = qi * 256 + r;
  short8 out;
  out[0] = f2b(acc0 * inv); out[1] = f2b(acc1 * inv);
  out[2] = f2b(acc2 * inv); out[3] = f2b(acc3 * inv);
  out[4] = f2b(acc4 * inv); out[5] = f2b(acc5 * inv);
  out[6] = f2b(acc6 * inv); out[7] = f2b(acc7 * inv);
  *(short8*)&Oh[((long)(b * 2048 + s)) * 1024 + h * 64 + d0] = out;
}

// ---------------------------------------------------------------- launch
extern "C" void kernel_launch(void* const* d_in, const int* in_sizes, int n_in,
                              void* d_out, int out_size, void* d_ws, size_t ws_size,
                              hipStream_t stream) {
  const float* x  = (const float*)d_in[0];
  const float* wq = (const float*)d_in[1];
  const float* wk = (const float*)d_in[2];
  const float* wv = (const float*)d_in[3];
  const float* wo = (const float*)d_in[4];
  const int* tok  = (const int*)d_in[5];

  short* wsp  = (short*)d_ws;
  short* xb   = wsp;                    //  4M shorts
  short* wqkv = xb + 4194304;           //  3M (dead after gemm256)
  short* wob  = wqkv + 3145728;         //  1M (live until final gemm)
  short* qkv  = wob + 1048576;          // 12M
  short* qh   = qkv + 12582912;         //  4M
  short* kh   = qh + 4194304;           //  4M
  short* vt   = kh + 4194304;           //  4M
  short* oh   = vt + 4194304;           //  4M

  short* vlin = qkv + 8388608;          // V linear [bs][1024] (read by vtrans)
  // attention partials overlay regions dead during attn:
  //   poO: qkv region, 640 pids * 256 rows * 64 = 10.49M shorts (< 12M)
  //   pmb/plb: xb region, 2 * 640*256 f32 = 1.31MB
  short* poO = qkv;
  float* pmb = (float*)xb;
  float* plb = pmb + NCHUNK2 * NBH * 256;

  (void)in_sizes; (void)n_in; (void)out_size; (void)ws_size;

  cvt_all<<<8192, 256, 0, stream>>>(x, wq, wk, wv, wo, xb, wqkv, wob);
  gemm256<<<256, 512, 0, stream>>>(xb, wqkv, tok, qh, kh, vlin);
  vtrans<<<dim3(32, 32), 256, 0, stream>>>(vlin, vt);
  attn_fwd<<<dim3(32, NCHUNK2), 256, 0, stream>>>(qh, kh, vt, poO, pmb, plb);
  attn_combine<<<dim3(64, 32), 256, 0, stream>>>(poO, pmb, plb, oh);
  gemm_fin<<<256, 256, 0, stream>>>(oh, wob, (float*)d_out);
}

// Round 18
// 118.192 us; speedup vs baseline: 1.1590x; 1.1590x over previous
//
#include <hip/hip_runtime.h>
#include <hip/hip_bf16.h>
#include <stdint.h>

// Problem constants
#define SEQL   2048
#define NBATCH 2
#define BSZ    4096   // NBATCH*SEQL
#define DMODEL 1024
#define NH     16
#define DK     64
#define NBH    32     // NBATCH*NH
#define NCHUNK_TOT 40 // sum over qi of ceil((2qi+2)/8)

typedef __attribute__((ext_vector_type(8)))  short short8;
typedef __attribute__((ext_vector_type(4)))  short shortx4;
typedef __attribute__((ext_vector_type(4)))  float f32x4;
typedef __attribute__((ext_vector_type(16))) float f32x16;
typedef __attribute__((ext_vector_type(4)))  unsigned uint4v;
union PU { uint4v u; short8 s; };

__device__ __forceinline__ short f2b(float f) {   // f32 -> bf16 (RNE)
  unsigned u = __float_as_uint(f);
  u = (u + 0x7FFF + ((u >> 16) & 1)) >> 16;
  return (short)u;
}
__device__ __forceinline__ float b2f(short s) {
  return __uint_as_float(((unsigned)(unsigned short)s) << 16);
}
__device__ __forceinline__ unsigned cvtpk(float lo, float hi) {
  unsigned r;
  asm("v_cvt_pk_bf16_f32 %0, %1, %2" : "=v"(r) : "v"(lo), "v"(hi));
  return r;
}
// swap a's upper-32-lane half with b's lower-32-lane half (in place)
#define PLSWAP(a_, b_) asm("v_permlane32_swap_b32 %0, %1" : "+v"(a_), "+v"(b_))

// async global->LDS, 16B per lane. LDS dest = wave-uniform base + lane*16.
__device__ __forceinline__ void g2l16(const void* g, void* l) {
  __builtin_amdgcn_global_load_lds(
      (__attribute__((address_space(1))) void*)(uintptr_t)g,
      (__attribute__((address_space(3))) void*)l, 16, 0, 0);
}

__device__ __forceinline__ f32x4 mfma16(short8 a, short8 b, f32x4 c) {
  return __builtin_amdgcn_mfma_f32_16x16x32_bf16(a, b, c, 0, 0, 0);
}
__device__ __forceinline__ f32x16 mfma32(short8 a, short8 b, f32x16 c) {
  return __builtin_amdgcn_mfma_f32_32x32x16_bf16(a, b, c, 0, 0, 0);
}

// ---------------------------------------------------------------- cvt f32->bf16
__global__ void cvt_all(const float* __restrict__ x,  const float* __restrict__ wq,
                        const float* __restrict__ wk, const float* __restrict__ wv,
                        const float* __restrict__ wo, short* __restrict__ xb,
                        short* __restrict__ wqkv, short* __restrict__ wob) {
  long idx = ((long)blockIdx.x * 256 + threadIdx.x) * 4;
  const float* s; short* d; long off;
  if (idx < 4194304L)      { s = x;  d = xb;             off = idx; }
  else if (idx < 5242880L) { s = wq; d = wqkv;           off = idx - 4194304L; }
  else if (idx < 6291456L) { s = wk; d = wqkv + 1048576; off = idx - 5242880L; }
  else if (idx < 7340032L) { s = wv; d = wqkv + 2097152; off = idx - 6291456L; }
  else                     { s = wo; d = wob;            off = idx - 7340032L; }
  float4 v = *(const float4*)(s + off);
  shortx4 r;
  r[0] = f2b(v.x); r[1] = f2b(v.y); r[2] = f2b(v.z); r[3] = f2b(v.w);
  *(shortx4*)(d + off) = r;
}

// ---------------------------------------------------------------- QKV GEMM, 256x192
// (R15 2-hazard schedule, measured best.)
__global__ __launch_bounds__(512, 1)
void gemm256(const short* __restrict__ A, const short* __restrict__ B,
             const int* __restrict__ tok, short* __restrict__ qh,
             short* __restrict__ kh, short* __restrict__ vlin) {
  __shared__ short As[2][16384];
  __shared__ short Bs[2][12288];
  int id = blockIdx.x;                    // 256 blocks
  int swz = (id & 7) * 32 + (id >> 3);    // XCD-bijective
  int bm = swz >> 4, bn = swz & 15;
  int brow = bm << 8, bcoln = bn * 192;
  int tid = threadIdx.x, w = tid >> 6;
  int wm = w >> 2, wn = w & 3;
  int lr = tid & 15, lg = (tid >> 4) & 3;
  const short* Abase = A + (long)brow * 1024;
  const short* Bbase = B + (long)bcoln * 1024;

  f32x4 acc[8][3];
#pragma unroll
  for (int mi = 0; mi < 8; ++mi)
#pragma unroll
    for (int ni = 0; ni < 3; ++ni) acc[mi][ni] = (f32x4){0.f, 0.f, 0.f, 0.f};

#define STGA(s_, kt_, buf_) do {                                                \
    int r_ = tid >> 3, gch_ = (tid & 7) ^ (r_ & 7);                             \
    g2l16(Abase + (long)((s_) * 64 + r_) * 1024 + (kt_) * 64 + gch_ * 8,        \
          &As[buf_][(s_) * 4096 + tid * 8]); } while (0)
#define STGB(s_, kt_, buf_) do {                                                \
    int r_ = tid >> 3, gch_ = (tid & 7) ^ (r_ & 7);                             \
    g2l16(Bbase + (long)((s_) * 64 + r_) * 1024 + (kt_) * 64 + gch_ * 8,        \
          &Bs[buf_][(s_) * 4096 + tid * 8]); } while (0)

  STGA(0,0,0); STGA(1,0,0); STGA(2,0,0); STGA(3,0,0);
  STGB(0,0,0); STGB(1,0,0); STGB(2,0,0);
  STGA(0,1,1); STGA(1,1,1); STGA(2,1,1); STGA(3,1,1);
  STGB(0,1,1); STGB(1,1,1); STGB(2,1,1);
  asm volatile("s_waitcnt vmcnt(7)" ::: "memory");
  __builtin_amdgcn_s_barrier();

  for (int kt = 0; kt < 16; ++kt) {
    int cur = kt & 1;
    const short* Ah = &As[cur][wm * 8192];
    const short* Bh = &Bs[cur][0];
    short8 a0[4][2], a1[4][2], bf[3][2];
#pragma unroll
    for (int mi = 0; mi < 4; ++mi) {
      int rin = mi * 16 + lr;
#pragma unroll
      for (int ks = 0; ks < 2; ++ks)
        a0[mi][ks] = *(const short8*)
            &Ah[rin * 64 + (((ks * 4 + lg) ^ (rin & 7)) << 3)];
    }
#pragma unroll
    for (int ni = 0; ni < 3; ++ni) {
      int ci = wn * 48 + ni * 16 + lr;
      int sub = ci >> 6, rin = ci & 63;
#pragma unroll
      for (int ks = 0; ks < 2; ++ks)
        bf[ni][ks] = *(const short8*)
            &Bh[sub * 4096 + rin * 64 + (((ks * 4 + lg) ^ (rin & 7)) << 3)];
    }
#pragma unroll
    for (int mi = 0; mi < 4; ++mi) {
      int rin = mi * 16 + lr;
#pragma unroll
      for (int ks = 0; ks < 2; ++ks)
        a1[mi][ks] = *(const short8*)
            &Ah[4096 + rin * 64 + (((ks * 4 + lg) ^ (rin & 7)) << 3)];
    }
    __builtin_amdgcn_s_setprio(1);
#pragma unroll
    for (int mi = 0; mi < 4; ++mi)
#pragma unroll
      for (int ni = 0; ni < 3; ++ni)
#pragma unroll
        for (int ks = 0; ks < 2; ++ks)
          acc[mi][ni] = mfma16(a0[mi][ks], bf[ni][ks], acc[mi][ni]);
    __builtin_amdgcn_s_setprio(0);
    asm volatile("s_waitcnt lgkmcnt(0)" ::: "memory");
    __builtin_amdgcn_s_barrier();
    if (kt + 2 < 16) {
      STGA(0, kt + 2, cur); STGA(1, kt + 2, cur);
      STGA(2, kt + 2, cur); STGA(3, kt + 2, cur);
      STGB(0, kt + 2, cur); STGB(1, kt + 2, cur); STGB(2, kt + 2, cur);
    }
    __builtin_amdgcn_s_setprio(1);
#pragma unroll
    for (int mi = 0; mi < 4; ++mi)
#pragma unroll
      for (int ni = 0; ni < 3; ++ni)
#pragma unroll
        for (int ks = 0; ks < 2; ++ks)
          acc[mi + 4][ni] = mfma16(a1[mi][ks], bf[ni][ks], acc[mi + 4][ni]);
    __builtin_amdgcn_s_setprio(0);
    if (kt + 1 < 16) {
      if (kt + 2 < 16) asm volatile("s_waitcnt vmcnt(7)" ::: "memory");
      else             asm volatile("s_waitcnt vmcnt(0)" ::: "memory");
    }
    __builtin_amdgcn_s_barrier();
  }
#undef STGA
#undef STGB

  // ---- epilogue: Q/K -> RoPE + head-split; V -> linear for vtrans.
  int sbase = brow + wm * 128;
#pragma unroll
  for (int ni = 0; ni < 3; ++ni) {
    int gcol = bcoln + wn * 48 + ni * 16 + lr;
    int mat = gcol >> 10;
    int cin = gcol & 1023;
    if (mat == 2) {
#pragma unroll
      for (int mi = 0; mi < 8; ++mi)
#pragma unroll
        for (int rr = 0; rr < 4; ++rr) {
          int grow = sbase + mi * 16 + lg * 4 + rr;
          vlin[(long)grow * 1024 + cin] = f2b(acc[mi][ni][rr]);
        }
    } else {
      short* dst = mat ? kh : qh;
      float scale = mat ? 1.0f : 0.125f * 1.44269504f;
      int d = cin & 63, h = cin >> 6;
      int i = d >> 1;
      int odd = d & 1;
      float frev = exp2f(-(float)i * 0.41524101186f) * 0.15915494309f;
#pragma unroll
      for (int mi = 0; mi < 8; ++mi)
#pragma unroll
        for (int rr = 0; rr < 4; ++rr) {
          int grow = sbase + mi * 16 + lg * 4 + rr;
          int s = grow & 2047, b = grow >> 11;
          float pos = (float)tok[s];
          float rev = pos * frev;
          float fr = rev - floorf(rev);
          float sn, cs;
          asm("v_sin_f32 %0, %1" : "=v"(sn) : "v"(fr));
          asm("v_cos_f32 %0, %1" : "=v"(cs) : "v"(fr));
          float v = acc[mi][ni][rr];
          float p = __shfl_xor(v, 1);
          float out = odd ? (p * sn + v * cs) : (v * cs - p * sn);
          dst[((long)(b * 16 + h) * 2048 + s) * 64 + d] = f2b(out * scale);
        }
    }
  }
}

// ---------------------------------------------------------------- final GEMM, 128x128, BK=64, 2-hazard
__global__ __launch_bounds__(256, 2)
void gemm_fin(const short* __restrict__ A, const short* __restrict__ B,
              float* __restrict__ C) {
  __shared__ short As[2][8192];
  __shared__ short Bs[2][8192];
  int bm = blockIdx.x >> 3, bn = blockIdx.x & 7;
  int tid = threadIdx.x, w = tid >> 6, l = tid & 63;
  int wm = w >> 1, wn = w & 1;
  int lr = l & 15, lg = l >> 4;
  int brow = bm << 7, bcol = bn << 7;
  const short* Abase = A + (long)brow * 1024;
  const short* Bbase = B + (long)bcol * 1024;

  const f32x4 fz = {0.f, 0.f, 0.f, 0.f};
  f32x4 acc[4][4];
#pragma unroll
  for (int xi = 0; xi < 4; ++xi)
#pragma unroll
    for (int yi = 0; yi < 4; ++yi) acc[xi][yi] = fz;

#define FSTG(kt_, buf_) do {                                                    \
    _Pragma("unroll")                                                           \
    for (int i_ = 0; i_ < 4; ++i_) {                                            \
      int idx_ = i_ * 256 + tid;                                                \
      int r_ = idx_ >> 3, gch_ = (idx_ & 7) ^ (r_ & 7);                         \
      g2l16(Abase + (long)r_ * 1024 + (kt_) * 64 + gch_ * 8,                    \
            &As[buf_][idx_ * 8]);                                               \
      g2l16(Bbase + (long)r_ * 1024 + (kt_) * 64 + gch_ * 8,                    \
            &Bs[buf_][idx_ * 8]);                                               \
    } } while (0)

  FSTG(0, 0);
  FSTG(1, 1);
  asm volatile("s_waitcnt vmcnt(8)" ::: "memory");
  __builtin_amdgcn_s_barrier();

  for (int kt = 0; kt < 16; ++kt) {
    int cur = kt & 1;
    short8 af[4][2], bfr[4][2];
#pragma unroll
    for (int xi = 0; xi < 4; ++xi) {
      int ar = wm * 64 + xi * 16 + lr;
      int br = wn * 64 + xi * 16 + lr;
#pragma unroll
      for (int ks = 0; ks < 2; ++ks) {
        af[xi][ks] = *(const short8*)
            &As[cur][ar * 64 + (((ks * 4 + lg) ^ (ar & 7)) << 3)];
        bfr[xi][ks] = *(const short8*)
            &Bs[cur][br * 64 + (((ks * 4 + lg) ^ (br & 7)) << 3)];
      }
    }
    __builtin_amdgcn_s_setprio(1);
#pragma unroll
    for (int xi = 0; xi < 4; ++xi)
#pragma unroll
      for (int yi = 0; yi < 4; ++yi)
        acc[xi][yi] = mfma16(af[xi][0], bfr[yi][0], acc[xi][yi]);
    __builtin_amdgcn_s_setprio(0);
    asm volatile("s_waitcnt lgkmcnt(0)" ::: "memory");
    __builtin_amdgcn_s_barrier();
    if (kt + 2 < 16) FSTG(kt + 2, cur);
    __builtin_amdgcn_s_setprio(1);
#pragma unroll
    for (int xi = 0; xi < 4; ++xi)
#pragma unroll
      for (int yi = 0; yi < 4; ++yi)
        acc[xi][yi] = mfma16(af[xi][1], bfr[yi][1], acc[xi][yi]);
    __builtin_amdgcn_s_setprio(0);
    if (kt + 1 < 16) {
      if (kt + 2 < 16) asm volatile("s_waitcnt vmcnt(8)" ::: "memory");
      else             asm volatile("s_waitcnt vmcnt(0)" ::: "memory");
    }
    __builtin_amdgcn_s_barrier();
  }
#undef FSTG

#pragma unroll
  for (int xi = 0; xi < 4; ++xi)
#pragma unroll
    for (int yi = 0; yi < 4; ++yi)
#pragma unroll
      for (int r = 0; r < 4; ++r) {
        int row = brow + wm * 64 + xi * 16 + lg * 4 + r;
        int col = bcol + wn * 64 + yi * 16 + lr;
        C[(long)row * 1024 + col] = acc[xi][yi][r];
      }
}

// ---------------------------------------------------------------- V transpose
__global__ void vtrans(const short* __restrict__ Vlin, short* __restrict__ Vt) {
  __shared__ short tile[64][72];
  int s0 = blockIdx.x * 64;
  int bh = blockIdx.y;
  int b = bh >> 4, h = bh & 15;
  int t = threadIdx.x;
  int r = t >> 2, c0 = (t & 3) * 16;
  const short* src = Vlin + ((long)(b * 2048 + s0 + r)) * 1024 + h * 64 + c0;
  *(short8*)&tile[r][c0]     = *(const short8*)src;
  *(short8*)&tile[r][c0 + 8] = *(const short8*)(src + 8);
  __syncthreads();
  int d = t >> 2, sc0 = (t & 3) * 16;
  short8 o0, o1;
#pragma unroll
  for (int j = 0; j < 8; ++j) { o0[j] = tile[sc0 + j][d]; o1[j] = tile[sc0 + 8 + j][d]; }
  short* dst = Vt + ((long)(bh * 64 + d)) * 2048 + s0 + sc0;
  *(short8*)dst       = o0;
  *(short8*)(dst + 8) = o1;
}

// ---------------------------------------------------------------- causal flash attention, split-KV
// (R8-measured best) grid (NBH, 40): bh -> XCD pin; chunks heavy-first.
// 4 waves x 32 q-rows. 3-deep LDS pipeline (48KB), counted vmcnt(8). log2 domain.
__global__ __launch_bounds__(256, 3)
void attn_fwd(const short* __restrict__ Qh, const short* __restrict__ Kh,
              const short* __restrict__ Vt, short* __restrict__ poO,
              float* __restrict__ pmb, float* __restrict__ plb) {
  __shared__ short Ks[3][4096];
  __shared__ short Vs[3][4096];
  int bh = blockIdx.x;
  int xr = 39 - blockIdx.y;
  int qi, c = xr, nc = 1;
  for (qi = 0; qi < 16; ++qi) { nc = (qi >> 2) + 1; if (c < nc) break; c -= nc; }
  int n = 2 * qi + 2;
  int t0 = (c * n) / nc, t1 = ((c + 1) * n) / nc;
  int q0b = qi << 7;
  int tid = threadIdx.x, w = tid >> 6, l = tid & 63;
  int ql = l & 31, hi = l >> 5;
  const short* Qb = Qh + (long)bh * (2048 * 64);
  const short* Kb = Kh + (long)bh * (2048 * 64);
  const short* Vb = Vt + (long)bh * (64 * 2048);
  int qw = q0b + 32 * w;
  int qg = qw + ql;
  int pid = bh * NCHUNK_TOT + xr;

  short8 qf[4];
#pragma unroll
  for (int kc = 0; kc < 4; ++kc)
    qf[kc] = *(const short8*)(Qb + (long)qg * 64 + kc * 16 + hi * 8);

  f32x16 o0, o1;
#pragma unroll
  for (int r = 0; r < 16; ++r) { o0[r] = 0.f; o1[r] = 0.f; }
  float m = -1e30f, lsum = 0.f;

#define STAGE(t_, bufi_) do {                                                   \
    int s0_ = (t_) << 6;                                                        \
    _Pragma("unroll")                                                           \
    for (int i_ = 0; i_ < 2; ++i_) {                                            \
      int c_ = w + 4 * i_;                                                      \
      int g_ = c_ >> 2, cc_ = c_ & 3;                                           \
      g2l16(Kb + ((long)(s0_ + g_ * 32 + ql)) * 64 + cc_ * 16 + hi * 8,         \
            &Ks[bufi_][c_ * 512]);                                              \
      g2l16(Vb + ((long)(g_ * 32 + ql)) * 2048 + s0_ + cc_ * 16 + hi * 8,       \
            &Vs[bufi_][c_ * 512]);                                              \
    }                                                                           \
  } while (0)

  STAGE(t0, 0);
  if (t0 + 1 < t1) STAGE(t0 + 1, 1);
  int cur = 0;

  for (int t = t0; t < t1; ++t) {
    if (t + 2 < t1) {
      int nb = cur + 2; if (nb >= 3) nb -= 3;
      STAGE(t + 2, nb);
      asm volatile("s_waitcnt vmcnt(8)" ::: "memory");
    } else if (t + 1 < t1) {
      asm volatile("s_waitcnt vmcnt(4)" ::: "memory");
    } else {
      asm volatile("s_waitcnt vmcnt(0)" ::: "memory");
    }
    __builtin_amdgcn_s_barrier();
    int s0 = t << 6;
    if (s0 <= qw + 31) {
      bool upper = (s0 + 32 <= qw + 31);
      f32x16 sT0, sT1;
#pragma unroll
      for (int r = 0; r < 16; ++r) { sT0[r] = 0.f; sT1[r] = 0.f; }
      __builtin_amdgcn_s_setprio(1);
#pragma unroll
      for (int kc = 0; kc < 4; ++kc) {
        short8 k0 = *(const short8*)&Ks[cur][(kc * 64 + l) * 8];
        sT0 = mfma32(k0, qf[kc], sT0);
      }
      if (upper) {
#pragma unroll
        for (int kc = 0; kc < 4; ++kc) {
          short8 k1 = *(const short8*)&Ks[cur][((4 + kc) * 64 + l) * 8];
          sT1 = mfma32(k1, qf[kc], sT1);
        }
      }
      __builtin_amdgcn_s_setprio(0);
      if (s0 + 63 > qw) {
#pragma unroll
        for (int r = 0; r < 16; ++r) {
          int kvl = (r & 3) + 8 * (r >> 2) + 4 * hi;
          if (s0 + kvl > qg) sT0[r] = -1e30f;
        }
        if (upper) {
#pragma unroll
          for (int r = 0; r < 16; ++r) {
            int kvl = (r & 3) + 8 * (r >> 2) + 4 * hi;
            if (s0 + 32 + kvl > qg) sT1[r] = -1e30f;
          }
        }
      }
      float pmax = sT0[0];
#pragma unroll
      for (int r = 1; r < 16; ++r) pmax = fmaxf(pmax, sT0[r]);
      if (upper) {
#pragma unroll
        for (int r = 0; r < 16; ++r) pmax = fmaxf(pmax, sT1[r]);
      }
      pmax = fmaxf(pmax, __shfl_xor(pmax, 32));
      if (__any(pmax > m + 11.5416f)) {
        float mn = fmaxf(m, pmax);
        float sf = exp2f(m - mn);
        m = mn;
        lsum *= sf;
#pragma unroll
        for (int r = 0; r < 16; ++r) {
          int row = (r & 3) + 8 * (r >> 2) + 4 * hi;
          float fo = __shfl(sf, row);
          o0[r] *= fo; o1[r] *= fo;
        }
      }
      float rs = 0.f;
#pragma unroll
      for (int r = 0; r < 16; ++r) {
        float p = exp2f(sT0[r] - m);
        sT0[r] = p; rs += p;
      }
      if (upper) {
#pragma unroll
        for (int r = 0; r < 16; ++r) {
          float p = exp2f(sT1[r] - m);
          sT1[r] = p; rs += p;
        }
      }
      rs += __shfl_xor(rs, 32);
      lsum += rs;
      short8 pa[4];
      {
        unsigned cA[4], cB[4];
#pragma unroll
        for (int g = 0; g < 4; ++g) {
          cA[g] = cvtpk(sT0[4 * g], sT0[4 * g + 1]);
          cB[g] = cvtpk(sT0[4 * g + 2], sT0[4 * g + 3]);
        }
        PLSWAP(cA[0], cA[1]); PLSWAP(cB[0], cB[1]);
        PLSWAP(cA[2], cA[3]); PLSWAP(cB[2], cB[3]);
        PU p0; p0.u = (uint4v){cA[0], cB[0], cA[1], cB[1]}; pa[0] = p0.s;
        PU p1; p1.u = (uint4v){cA[2], cB[2], cA[3], cB[3]}; pa[1] = p1.s;
      }
      if (upper) {
        unsigned cA[4], cB[4];
#pragma unroll
        for (int g = 0; g < 4; ++g) {
          cA[g] = cvtpk(sT1[4 * g], sT1[4 * g + 1]);
          cB[g] = cvtpk(sT1[4 * g + 2], sT1[4 * g + 3]);
        }
        PLSWAP(cA[0], cA[1]); PLSWAP(cB[0], cB[1]);
        PLSWAP(cA[2], cA[3]); PLSWAP(cB[2], cB[3]);
        PU p2; p2.u = (uint4v){cA[0], cB[0], cA[1], cB[1]}; pa[2] = p2.s;
        PU p3; p3.u = (uint4v){cA[2], cB[2], cA[3], cB[3]}; pa[3] = p3.s;
      }
      __builtin_amdgcn_s_setprio(1);
#pragma unroll
      for (int kc = 0; kc < 2; ++kc) {
        short8 v0 = *(const short8*)&Vs[cur][(kc * 64 + l) * 8];
        short8 v1 = *(const short8*)&Vs[cur][((4 + kc) * 64 + l) * 8];
        o0 = mfma32(pa[kc], v0, o0);
        o1 = mfma32(pa[kc], v1, o1);
      }
      if (upper) {
#pragma unroll
        for (int kc = 2; kc < 4; ++kc) {
          short8 v0 = *(const short8*)&Vs[cur][(kc * 64 + l) * 8];
          short8 v1 = *(const short8*)&Vs[cur][((4 + kc) * 64 + l) * 8];
          o0 = mfma32(pa[kc], v0, o0);
          o1 = mfma32(pa[kc], v1, o1);
        }
      }
      __builtin_amdgcn_s_setprio(0);
    }
    asm volatile("s_waitcnt lgkmcnt(0)" ::: "memory");
    __builtin_amdgcn_s_barrier();
    ++cur; if (cur >= 3) cur -= 3;
  }
#undef STAGE

  if (hi == 0) {
    pmb[pid * 128 + w * 32 + ql] = m;
    plb[pid * 128 + w * 32 + ql] = lsum;
  }
#pragma unroll
  for (int r = 0; r < 16; ++r) {
    int row = (r & 3) + 8 * (r >> 2) + 4 * hi;
    long basep = ((long)pid * 128 + w * 32 + row) * 64;
    poO[basep + ql]      = f2b(o0[r]);
    poO[basep + 32 + ql] = f2b(o1[r]);
  }
}

// ---------------------------------------------------------------- combine partials
__global__ void attn_combine(const short* __restrict__ poO,
                             const float* __restrict__ pmb,
                             const float* __restrict__ plb,
                             short* __restrict__ Oh) {
  int x = blockIdx.x, bh = blockIdx.y;
  int qi = x >> 2, sub = x & 3;
  int t = threadIdx.x;
  int r = sub * 32 + (t >> 3);
  int d0 = (t & 7) * 8;
  int nc = (qi >> 2) + 1;
  int prefix = 0;
  for (int j = 0; j < qi; ++j) prefix += (j >> 2) + 1;
  int base = bh * NCHUNK_TOT + prefix;
  float M = -1e30f;
  for (int i = 0; i < nc; ++i)
    M = fmaxf(M, pmb[(base + i) * 128 + r]);
  float acc0 = 0, acc1 = 0, acc2 = 0, acc3 = 0, acc4 = 0, acc5 = 0, acc6 = 0, acc7 = 0;
  float den = 0.f;
  for (int i = 0; i < nc; ++i) {
    float wgt = exp2f(pmb[(base + i) * 128 + r] - M);
    den += wgt * plb[(base + i) * 128 + r];
    short8 ov = *(const short8*)&poO[((long)(base + i) * 128 + r) * 64 + d0];
    acc0 += wgt * b2f(ov[0]); acc1 += wgt * b2f(ov[1]);
    acc2 += wgt * b2f(ov[2]); acc3 += wgt * b2f(ov[3]);
    acc4 += wgt * b2f(ov[4]); acc5 += wgt * b2f(ov[5]);
    acc6 += wgt * b2f(ov[6]); acc7 += wgt * b2f(ov[7]);
  }
  float inv = 1.0f / den;
  int b = bh >> 4, h = bh & 15;
  int s = qi * 128 + r;
  short8 out;
  out[0] = f2b(acc0 * inv); out[1] = f2b(acc1 * inv);
  out[2] = f2b(acc2 * inv); out[3] = f2b(acc3 * inv);
  out[4] = f2b(acc4 * inv); out[5] = f2b(acc5 * inv);
  out[6] = f2b(acc6 * inv); out[7] = f2b(acc7 * inv);
  *(short8*)&Oh[((long)(b * 2048 + s)) * 1024 + h * 64 + d0] = out;
}

// ---------------------------------------------------------------- launch
extern "C" void kernel_launch(void* const* d_in, const int* in_sizes, int n_in,
                              void* d_out, int out_size, void* d_ws, size_t ws_size,
                              hipStream_t stream) {
  const float* x  = (const float*)d_in[0];
  const float* wq = (const float*)d_in[1];
  const float* wk = (const float*)d_in[2];
  const float* wv = (const float*)d_in[3];
  const float* wo = (const float*)d_in[4];
  const int* tok  = (const int*)d_in[5];

  short* wsp  = (short*)d_ws;
  short* xb   = wsp;                    //  4M shorts
  short* wqkv = xb + 4194304;           //  3M (dead after gemm256)
  short* wob  = wqkv + 3145728;         //  1M (live until final gemm)
  short* qkv  = wob + 1048576;          // 12M
  short* qh   = qkv + 12582912;         //  4M
  short* kh   = qh + 4194304;           //  4M
  short* vt   = kh + 4194304;           //  4M
  short* oh   = vt + 4194304;           //  4M

  short* vlin = qkv + 8388608;          // V linear [bs][1024] (read by vtrans)
  // attention partials overlay regions dead during attn:
  short* poO = qkv;                     // 1280*128*64 bf16 = 10.5M shorts (< 12M)
  float* pmb = (float*)xb;              // 1280*128 f32
  float* plb = pmb + NCHUNK_TOT * NBH * 128;

  (void)in_sizes; (void)n_in; (void)out_size; (void)ws_size;

  cvt_all<<<8192, 256, 0, stream>>>(x, wq, wk, wv, wo, xb, wqkv, wob);
  gemm256<<<256, 512, 0, stream>>>(xb, wqkv, tok, qh, kh, vlin);
  vtrans<<<dim3(32, 32), 256, 0, stream>>>(vlin, vt);
  attn_fwd<<<dim3(32, NCHUNK_TOT), 256, 0, stream>>>(qh, kh, vt, poO, pmb, plb);
  attn_combine<<<dim3(64, 32), 256, 0, stream>>>(poO, pmb, plb, oh);
  gemm_fin<<<256, 256, 0, stream>>>(oh, wob, (float*)d_out);
}